// Round 4
// baseline (113.936 us; speedup 1.0000x reference)
//
#include <hip/hip_runtime.h>
#include <hip/hip_bf16.h>
#include <math.h>

// Problem constants: B=2, L=512, D=1024, H=16, DH=64. N = B*L = 1024.

typedef unsigned short ushort_t;
typedef __attribute__((ext_vector_type(8))) short bf16x8;
typedef __attribute__((ext_vector_type(4))) float f32x4;

__device__ __forceinline__ float sigmoidf_(float z) { return 1.f / (1.f + expf(-z)); }

__device__ __forceinline__ ushort_t f2bf(float f) {
    __hip_bfloat16 h = __float2bfloat16(f);
    return *reinterpret_cast<ushort_t*>(&h);
}

// ---------------------------------------------------------------------------
// Convert 5 fp32 1M-element arrays to bf16 (x, q1w, k1w, k2w, cpw).
// ---------------------------------------------------------------------------
__global__ __launch_bounds__(256) void cvt5(const float* __restrict__ s0, const float* __restrict__ s1,
                                            const float* __restrict__ s2, const float* __restrict__ s3,
                                            const float* __restrict__ s4,
                                            ushort_t* __restrict__ d0, ushort_t* __restrict__ d1,
                                            ushort_t* __restrict__ d2, ushort_t* __restrict__ d3,
                                            ushort_t* __restrict__ d4) {
    const int t = blockIdx.x * 256 + threadIdx.x;
    const int arr = t >> 17;
    const int off = (t & 131071) * 8;
    const float* s = arr == 0 ? s0 : arr == 1 ? s1 : arr == 2 ? s2 : arr == 3 ? s3 : s4;
    ushort_t* d = arr == 0 ? d0 : arr == 1 ? d1 : arr == 2 ? d2 : arr == 3 ? d3 : d4;
    float4 a = *reinterpret_cast<const float4*>(s + off);
    float4 b = *reinterpret_cast<const float4*>(s + off + 4);
    union { uint4 v; ushort_t u[8]; } pk;
    pk.u[0] = f2bf(a.x); pk.u[1] = f2bf(a.y); pk.u[2] = f2bf(a.z); pk.u[3] = f2bf(a.w);
    pk.u[4] = f2bf(b.x); pk.u[5] = f2bf(b.y); pk.u[6] = f2bf(b.z); pk.u[7] = f2bf(b.w);
    *reinterpret_cast<uint4*>(d + off) = pk.v;
}

// ---------------------------------------------------------------------------
// bf16 MFMA GEMM: Out[sel] = A @ W[sel] + bias[sel] (fp32 out). 64x64 tile.
// ---------------------------------------------------------------------------
__global__ __launch_bounds__(256) void gemm_mfma(const ushort_t* __restrict__ Ab,
                                                 const ushort_t* __restrict__ W0,
                                                 const ushort_t* __restrict__ W1,
                                                 const ushort_t* __restrict__ W2,
                                                 const float* __restrict__ b0,
                                                 const float* __restrict__ b1,
                                                 const float* __restrict__ b2,
                                                 float* __restrict__ O0,
                                                 float* __restrict__ O1,
                                                 float* __restrict__ O2,
                                                 int out_fp32) {
    const int sel = blockIdx.z;
    const ushort_t* Wb = sel == 0 ? W0 : sel == 1 ? W1 : W2;
    const float* bias = sel == 0 ? b0 : sel == 1 ? b1 : b2;
    float* Out = sel == 0 ? O0 : sel == 1 ? O1 : O2;
    const int m0 = blockIdx.y * 64, n0 = blockIdx.x * 64;

    __shared__ ushort_t As[64][72];
    __shared__ ushort_t Bs[64][72];

    const int tid = threadIdx.x;
    const int wave = tid >> 6, lane = tid & 63;
    const int l15 = lane & 15, lq = lane >> 4;

    const int arow = tid >> 2;
    const int ak = (tid & 3) * 16;
    const int bk = tid >> 2;
    const int bn = (tid & 3) * 16;

    f32x4 acc[4];
#pragma unroll
    for (int i = 0; i < 4; ++i) acc[i] = (f32x4){0.f, 0.f, 0.f, 0.f};

    for (int k0 = 0; k0 < 1024; k0 += 64) {
        uint4 av0 = *reinterpret_cast<const uint4*>(Ab + (size_t)(m0 + arow) * 1024 + k0 + ak);
        uint4 av1 = *reinterpret_cast<const uint4*>(Ab + (size_t)(m0 + arow) * 1024 + k0 + ak + 8);
        union { uint4 v; ushort_t u[8]; } bu0, bu1;
        bu0.v = *reinterpret_cast<const uint4*>(Wb + (size_t)(k0 + bk) * 1024 + n0 + bn);
        bu1.v = *reinterpret_cast<const uint4*>(Wb + (size_t)(k0 + bk) * 1024 + n0 + bn + 8);
        __syncthreads();
        *reinterpret_cast<uint4*>(&As[arow][ak]) = av0;
        *reinterpret_cast<uint4*>(&As[arow][ak + 8]) = av1;
#pragma unroll
        for (int j = 0; j < 8; ++j) Bs[bn + j][bk] = bu0.u[j];
#pragma unroll
        for (int j = 0; j < 8; ++j) Bs[bn + 8 + j][bk] = bu1.u[j];
        __syncthreads();

#pragma unroll
        for (int kk = 0; kk < 64; kk += 32) {
            bf16x8 a = *reinterpret_cast<const bf16x8*>(&As[16 * wave + l15][kk + 8 * lq]);
#pragma unroll
            for (int nt = 0; nt < 4; ++nt) {
                bf16x8 b = *reinterpret_cast<const bf16x8*>(&Bs[16 * nt + l15][kk + 8 * lq]);
                acc[nt] = __builtin_amdgcn_mfma_f32_16x16x32_bf16(a, b, acc[nt], 0, 0, 0);
            }
        }
    }

#pragma unroll
    for (int nt = 0; nt < 4; ++nt) {
        const int col = n0 + 16 * nt + l15;
        const float bcol = bias[col];
#pragma unroll
        for (int r = 0; r < 4; ++r) {
            const int row = m0 + 16 * wave + 4 * lq + r;
            Out[(size_t)row * 1024 + col] = acc[nt][r] + bcol;
        }
    }
    (void)out_fp32;
}

// ---------------------------------------------------------------------------
// Fused per-(b,h) chunked linear attention. One block = one (b,h), 512 thr.
// State S[64d][64e] lives in registers (each of 8 waves owns two 16x16 tiles).
// 8 chunks of 64 sequential. Per chunk:
//   A: write SBt (bf16 S^T copy) + stage Q/K'/K'^T/V'^T tiles (bf16 in LDS)
//   B: scores = Q @ K'^T, causal mask -> Ps (bf16)
//   C: out = Q @ S_exc + Ps @ V'  (MFMA), state += K'^T @ V' (MFMA), epilogue
// MODE 0 (GLA): K' = a*K, V' = x; out *= Gc -> O1 (fp32). Scan in prologue.
// MODE 1 (MA):  K' = sigmoid(C2/32*.02), V' = x[tau+1]-O1[tau];
//               yout[t'+1] = bf16(O1[t'+1] + out[t']), yout[0] = bf16(O1[0]).
// ---------------------------------------------------------------------------
template <int MODE>
__global__ __launch_bounds__(512) void fused_attn(const float* __restrict__ x,
                                                  const float* __restrict__ Qb,
                                                  const float* __restrict__ Kb,
                                                  const float* __restrict__ C2,
                                                  const float* __restrict__ O1in,
                                                  const float* __restrict__ gw_w,
                                                  const float* __restrict__ gw_b,
                                                  const float* __restrict__ sw_w,
                                                  const float* __restrict__ sw_b,
                                                  float* __restrict__ O1out,
                                                  ushort_t* __restrict__ yout) {
    const int bh = blockIdx.x;
    const int b = bh >> 4, h = bh & 15;
    const int tid = threadIdx.x;
    const int w = tid >> 6, lane = tid & 63;
    const int l15 = lane & 15, lq = lane >> 4;
    const int tw = w >> 1;            // t-tile (and d-tile) owned by this wave
    const int ew0 = 2 * (w & 1);      // first of two e/c-tiles owned

    __shared__ ushort_t Qs[64][72];   // [t][d]
    __shared__ ushort_t Ks[64][72];   // [c][d]
    __shared__ ushort_t KT[64][72];   // [d][c]
    __shared__ ushort_t VT[64][72];   // [e][tau]
    __shared__ ushort_t Ps[64][72];   // [t][c]
    __shared__ ushort_t SBt[64][72];  // [e][d]  bf16 copy of state S^T
    __shared__ float gcl[512];
    __shared__ float abl[512];
    __shared__ float gwl[64], swl[64];
    __shared__ float wtot[8], offs[8];

    const size_t base = (size_t)(b * 512) * 1024 + h * 64;

    // ---- prologue: gate scan (MODE 0 only) ----
    if (MODE == 0) {
        if (tid < 64) gwl[tid] = gw_w[tid];
        else if (tid < 128) swl[tid - 64] = sw_w[tid - 64];
        __syncthreads();
        const float gwb = gw_b[0], swb = sw_b[0];
        const int t = tid;  // w*64 + lane
        const float* xr = x + base + (size_t)t * 1024;
        const float* kr = Kb + base + (size_t)t * 1024;
        float dg = 0.f, dk = 0.f;
#pragma unroll
        for (int d = 0; d < 64; d += 4) {
            float4 xv = *reinterpret_cast<const float4*>(xr + d);
            float4 kv = *reinterpret_cast<const float4*>(kr + d);
            dg += xv.x * gwl[d] + xv.y * gwl[d + 1] + xv.z * gwl[d + 2] + xv.w * gwl[d + 3];
            dk += kv.x * swl[d] + kv.y * swl[d + 1] + kv.z * swl[d + 2] + kv.w * swl[d + 3];
        }
        const float g = sigmoidf_(dg + gwb);
        float lg = logf(fmaxf(g, 1e-6f));
        float ps = lg;
#pragma unroll
        for (int off = 1; off < 64; off <<= 1) {
            float v = __shfl_up(ps, off, 64);
            if (lane >= off) ps += v;
        }
        if (lane == 63) wtot[w] = ps;
        __syncthreads();
        if (tid == 0) {
            float s = 0.f;
#pragma unroll
            for (int k = 0; k < 8; ++k) { offs[k] = s; s += wtot[k]; }
        }
        __syncthreads();
        const float lsum = offs[w] + ps;
        const float lclip = fminf(fmaxf(lsum, -30.f), 30.f);
        const float Gc = expf(lclip) + 1e-6f;
        const float z = dk + swb;
        gcl[t] = Gc;
        abl[t] = z * sigmoidf_(z) / Gc;
    }
    if (MODE == 1 && tid < 64) {  // row 0 of this batch: y = O1[0]
        yout[(size_t)(b * 512) * 1024 + h * 64 + tid] = f2bf(O1in[base + tid]);
    }
    __syncthreads();

    // ---- state registers ----
    f32x4 st[2];
    st[0] = (f32x4){0.f, 0.f, 0.f, 0.f};
    st[1] = (f32x4){0.f, 0.f, 0.f, 0.f};

    for (int j = 0; j < 8; ++j) {
        const int c0 = j * 64;

        // ---- phase A: SBt from state regs + stage tiles ----
#pragma unroll
        for (int i = 0; i < 2; ++i) {
            const int et = ew0 + i;
#pragma unroll
            for (int r = 0; r < 4; ++r)
                SBt[16 * et + l15][16 * tw + 4 * lq + r] = f2bf(st[i][r]);
        }
#pragma unroll
        for (int it = 0; it < 2; ++it) {
            const int idx = tid + it * 512;
            const int rr = idx >> 4;
            const int c4 = (idx & 15) << 2;
            const int tau = c0 + rr;
            float4 qv = *reinterpret_cast<const float4*>(&Qb[base + (size_t)tau * 1024 + c4]);
            float4 kv, vv;
            if (MODE == 0) {
                kv = *reinterpret_cast<const float4*>(&Kb[base + (size_t)tau * 1024 + c4]);
                const float a = abl[tau];
                kv.x *= a; kv.y *= a; kv.z *= a; kv.w *= a;
                vv = *reinterpret_cast<const float4*>(&x[base + (size_t)tau * 1024 + c4]);
            } else {
                qv.x = (qv.x < 0.f ? qv.x : 0.02f * qv.x) * 0.125f;
                qv.y = (qv.y < 0.f ? qv.y : 0.02f * qv.y) * 0.125f;
                qv.z = (qv.z < 0.f ? qv.z : 0.02f * qv.z) * 0.125f;
                qv.w = (qv.w < 0.f ? qv.w : 0.02f * qv.w) * 0.125f;
                if (tau <= 510) {
                    float4 cv = *reinterpret_cast<const float4*>(&C2[base + (size_t)tau * 1024 + c4]);
                    kv.x = sigmoidf_(cv.x * 6.25e-4f);
                    kv.y = sigmoidf_(cv.y * 6.25e-4f);
                    kv.z = sigmoidf_(cv.z * 6.25e-4f);
                    kv.w = sigmoidf_(cv.w * 6.25e-4f);
                    float4 xv = *reinterpret_cast<const float4*>(&x[base + (size_t)(tau + 1) * 1024 + c4]);
                    float4 ov = *reinterpret_cast<const float4*>(&O1in[base + (size_t)tau * 1024 + c4]);
                    vv.x = xv.x - ov.x; vv.y = xv.y - ov.y; vv.z = xv.z - ov.z; vv.w = xv.w - ov.w;
                } else {
                    kv.x = kv.y = kv.z = kv.w = 0.f;
                    vv.x = vv.y = vv.z = vv.w = 0.f;
                }
            }
            Qs[rr][c4 + 0] = f2bf(qv.x); Qs[rr][c4 + 1] = f2bf(qv.y);
            Qs[rr][c4 + 2] = f2bf(qv.z); Qs[rr][c4 + 3] = f2bf(qv.w);
            const ushort_t k0b = f2bf(kv.x), k1b = f2bf(kv.y), k2b = f2bf(kv.z), k3b = f2bf(kv.w);
            Ks[rr][c4 + 0] = k0b; Ks[rr][c4 + 1] = k1b; Ks[rr][c4 + 2] = k2b; Ks[rr][c4 + 3] = k3b;
            KT[c4 + 0][rr] = k0b; KT[c4 + 1][rr] = k1b; KT[c4 + 2][rr] = k2b; KT[c4 + 3][rr] = k3b;
            VT[c4 + 0][rr] = f2bf(vv.x); VT[c4 + 1][rr] = f2bf(vv.y);
            VT[c4 + 2][rr] = f2bf(vv.z); VT[c4 + 3][rr] = f2bf(vv.w);
        }
        __syncthreads();

        // ---- phase B: scores ----
        {
            f32x4 sc[2];
            sc[0] = (f32x4){0.f, 0.f, 0.f, 0.f};
            sc[1] = (f32x4){0.f, 0.f, 0.f, 0.f};
#pragma unroll
            for (int kk = 0; kk < 64; kk += 32) {
                bf16x8 a = *reinterpret_cast<const bf16x8*>(&Qs[16 * tw + l15][kk + 8 * lq]);
#pragma unroll
                for (int i = 0; i < 2; ++i) {
                    bf16x8 bb = *reinterpret_cast<const bf16x8*>(&Ks[16 * (ew0 + i) + l15][kk + 8 * lq]);
                    sc[i] = __builtin_amdgcn_mfma_f32_16x16x32_bf16(a, bb, sc[i], 0, 0, 0);
                }
            }
#pragma unroll
            for (int i = 0; i < 2; ++i) {
                const int c = 16 * (ew0 + i) + l15;
#pragma unroll
                for (int r = 0; r < 4; ++r) {
                    const int t = 16 * tw + 4 * lq + r;
                    Ps[t][c] = f2bf(c <= t ? sc[i][r] : 0.f);
                }
            }
        }
        __syncthreads();

        // ---- phase C: out MFMAs + state update + epilogue ----
        f32x4 oc[2];
        oc[0] = (f32x4){0.f, 0.f, 0.f, 0.f};
        oc[1] = (f32x4){0.f, 0.f, 0.f, 0.f};
#pragma unroll
        for (int kk = 0; kk < 64; kk += 32) {
            bf16x8 aq = *reinterpret_cast<const bf16x8*>(&Qs[16 * tw + l15][kk + 8 * lq]);
            bf16x8 ap = *reinterpret_cast<const bf16x8*>(&Ps[16 * tw + l15][kk + 8 * lq]);
            bf16x8 ak = *reinterpret_cast<const bf16x8*>(&KT[16 * tw + l15][kk + 8 * lq]);
#pragma unroll
            for (int i = 0; i < 2; ++i) {
                const int et = ew0 + i;
                bf16x8 sb = *reinterpret_cast<const bf16x8*>(&SBt[16 * et + l15][kk + 8 * lq]);
                oc[i] = __builtin_amdgcn_mfma_f32_16x16x32_bf16(aq, sb, oc[i], 0, 0, 0);
                bf16x8 vb = *reinterpret_cast<const bf16x8*>(&VT[16 * et + l15][kk + 8 * lq]);
                oc[i] = __builtin_amdgcn_mfma_f32_16x16x32_bf16(ap, vb, oc[i], 0, 0, 0);
                st[i] = __builtin_amdgcn_mfma_f32_16x16x32_bf16(ak, vb, st[i], 0, 0, 0);
            }
        }

        if (MODE == 0) {
#pragma unroll
            for (int r = 0; r < 4; ++r) {
                const int t = c0 + 16 * tw + 4 * lq + r;
                const float gcr = gcl[t];
#pragma unroll
                for (int i = 0; i < 2; ++i)
                    O1out[base + (size_t)t * 1024 + 16 * (ew0 + i) + l15] = gcr * oc[i][r];
            }
        } else {
#pragma unroll
            for (int r = 0; r < 4; ++r) {
                const int tp = c0 + 16 * tw + 4 * lq + r;
                if (tp <= 510) {
#pragma unroll
                    for (int i = 0; i < 2; ++i) {
                        const int e = 16 * (ew0 + i) + l15;
                        yout[(size_t)(b * 512 + tp + 1) * 1024 + h * 64 + e] =
                            f2bf(O1in[base + (size_t)(tp + 1) * 1024 + e] + oc[i][r]);
                    }
                }
            }
        }
        __syncthreads();
    }
}

// ---------------------------------------------------------------------------
extern "C" void kernel_launch(void* const* d_in, const int* in_sizes, int n_in,
                              void* d_out, int out_size, void* d_ws, size_t ws_size,
                              hipStream_t stream) {
    const float* x   = (const float*)d_in[0];
    const float* q1w = (const float*)d_in[1];
    const float* q1b = (const float*)d_in[2];
    const float* k1w = (const float*)d_in[3];
    const float* k1b = (const float*)d_in[4];
    const float* k2w = (const float*)d_in[5];
    const float* k2b = (const float*)d_in[6];
    const float* gww = (const float*)d_in[7];
    const float* gwb = (const float*)d_in[8];
    const float* sww = (const float*)d_in[9];
    const float* swb = (const float*)d_in[10];
    const float* cpw = (const float*)d_in[11];
    const float* cpb = (const float*)d_in[12];
    float* out = (float*)d_out;

    float* ws = (float*)d_ws;
    float* Q   = ws;                        // 1M floats
    float* K   = ws + 1048576;              // 1M
    float* C2  = ws + 2097152;              // 1M
    float* O1  = ws + 3145728;              // 1M
    ushort_t* xb  = (ushort_t*)(ws + 4194304);   // 1M ushorts each
    ushort_t* wqb = (ushort_t*)(ws + 4718592);
    ushort_t* wkb = (ushort_t*)(ws + 5242880);
    ushort_t* wcb = (ushort_t*)(ws + 5767168);
    ushort_t* wpb = (ushort_t*)(ws + 6291456);
    ushort_t* ytb = (ushort_t*)(ws + 6815744);
    // end: 7,340,032 floats = 29.4 MB

    cvt5<<<2560, 256, 0, stream>>>(x, q1w, k1w, k2w, cpw, xb, wqb, wkb, wcb, wpb);
    gemm_mfma<<<dim3(16, 16, 3), 256, 0, stream>>>(xb, wqb, wkb, wcb, q1b, k1b, k2b, Q, K, C2, 1);
    fused_attn<0><<<32, 512, 0, stream>>>(x, Q, K, C2, O1, gww, gwb, sww, swb, O1, ytb);
    fused_attn<1><<<32, 512, 0, stream>>>(x, Q, K, C2, O1, gww, gwb, sww, swb, O1, ytb);
    gemm_mfma<<<dim3(16, 16, 1), 256, 0, stream>>>(ytb, wpb, wpb, wpb, cpb, cpb, cpb, out, out, out, 1);
}

// Round 5
// 96.709 us; speedup vs baseline: 1.1781x; 1.1781x over previous
//
#include <hip/hip_runtime.h>
#include <hip/hip_bf16.h>
#include <math.h>

// Problem constants: B=2, L=512, D=1024, H=16, DH=64. N = B*L = 1024.

typedef unsigned short ushort_t;
typedef __attribute__((ext_vector_type(8))) short bf16x8;
typedef __attribute__((ext_vector_type(4))) float f32x4;

__device__ __forceinline__ float sigmoidf_(float z) { return 1.f / (1.f + expf(-z)); }

__device__ __forceinline__ ushort_t f2bf(float f) {
    __hip_bfloat16 h = __float2bfloat16(f);
    return *reinterpret_cast<ushort_t*>(&h);
}

// ---------------------------------------------------------------------------
// Convert 5 fp32 1M-element arrays to bf16 (x, q1w, k1w, k2w, cpw).
// ---------------------------------------------------------------------------
__global__ __launch_bounds__(256) void cvt5(const float* __restrict__ s0, const float* __restrict__ s1,
                                            const float* __restrict__ s2, const float* __restrict__ s3,
                                            const float* __restrict__ s4,
                                            ushort_t* __restrict__ d0, ushort_t* __restrict__ d1,
                                            ushort_t* __restrict__ d2, ushort_t* __restrict__ d3,
                                            ushort_t* __restrict__ d4) {
    const int t = blockIdx.x * 256 + threadIdx.x;
    const int arr = t >> 17;
    const int off = (t & 131071) * 8;
    const float* s = arr == 0 ? s0 : arr == 1 ? s1 : arr == 2 ? s2 : arr == 3 ? s3 : s4;
    ushort_t* d = arr == 0 ? d0 : arr == 1 ? d1 : arr == 2 ? d2 : arr == 3 ? d3 : d4;
    float4 a = *reinterpret_cast<const float4*>(s + off);
    float4 b = *reinterpret_cast<const float4*>(s + off + 4);
    union { uint4 v; ushort_t u[8]; } pk;
    pk.u[0] = f2bf(a.x); pk.u[1] = f2bf(a.y); pk.u[2] = f2bf(a.z); pk.u[3] = f2bf(a.w);
    pk.u[4] = f2bf(b.x); pk.u[5] = f2bf(b.y); pk.u[6] = f2bf(b.z); pk.u[7] = f2bf(b.w);
    *reinterpret_cast<uint4*>(d + off) = pk.v;
}

// ---------------------------------------------------------------------------
// bf16 MFMA GEMM: Out[sel] = A @ W[sel] + bias[sel] (fp32 out). 64x64 tile.
// B-transpose staged with paired b32 writes.
// ---------------------------------------------------------------------------
__global__ __launch_bounds__(256) void gemm_mfma(const ushort_t* __restrict__ Ab,
                                                 const ushort_t* __restrict__ W0,
                                                 const ushort_t* __restrict__ W1,
                                                 const ushort_t* __restrict__ W2,
                                                 const float* __restrict__ b0,
                                                 const float* __restrict__ b1,
                                                 const float* __restrict__ b2,
                                                 float* __restrict__ O0,
                                                 float* __restrict__ O1,
                                                 float* __restrict__ O2) {
    const int sel = blockIdx.z;
    const ushort_t* Wb = sel == 0 ? W0 : sel == 1 ? W1 : W2;
    const float* bias = sel == 0 ? b0 : sel == 1 ? b1 : b2;
    float* Out = sel == 0 ? O0 : sel == 1 ? O1 : O2;
    const int m0 = blockIdx.y * 64, n0 = blockIdx.x * 64;

    __shared__ ushort_t As[64][72];
    __shared__ ushort_t Bs[64][72];

    const int tid = threadIdx.x;
    const int wave = tid >> 6, lane = tid & 63;
    const int l15 = lane & 15, lq = lane >> 4;

    const int arow = tid >> 2;
    const int ak = (tid & 3) * 16;
    const int krow = (tid >> 3) * 2;    // 0,2,...,62
    const int ncol = (tid & 7) * 8;     // 0,8,...,56

    f32x4 acc[4];
#pragma unroll
    for (int i = 0; i < 4; ++i) acc[i] = (f32x4){0.f, 0.f, 0.f, 0.f};

    for (int k0 = 0; k0 < 1024; k0 += 64) {
        uint4 av0 = *reinterpret_cast<const uint4*>(Ab + (size_t)(m0 + arow) * 1024 + k0 + ak);
        uint4 av1 = *reinterpret_cast<const uint4*>(Ab + (size_t)(m0 + arow) * 1024 + k0 + ak + 8);
        union { uint4 v; ushort_t u[8]; } bu0, bu1;
        bu0.v = *reinterpret_cast<const uint4*>(Wb + (size_t)(k0 + krow) * 1024 + n0 + ncol);
        bu1.v = *reinterpret_cast<const uint4*>(Wb + (size_t)(k0 + krow + 1) * 1024 + n0 + ncol);
        __syncthreads();
        *reinterpret_cast<uint4*>(&As[arow][ak]) = av0;
        *reinterpret_cast<uint4*>(&As[arow][ak + 8]) = av1;
#pragma unroll
        for (int jj = 0; jj < 8; ++jj) {
            const unsigned int pair = (unsigned int)bu0.u[jj] | ((unsigned int)bu1.u[jj] << 16);
            *reinterpret_cast<unsigned int*>(&Bs[ncol + jj][krow]) = pair;
        }
        __syncthreads();

#pragma unroll
        for (int kk = 0; kk < 64; kk += 32) {
            bf16x8 a = *reinterpret_cast<const bf16x8*>(&As[16 * wave + l15][kk + 8 * lq]);
#pragma unroll
            for (int nt = 0; nt < 4; ++nt) {
                bf16x8 b = *reinterpret_cast<const bf16x8*>(&Bs[16 * nt + l15][kk + 8 * lq]);
                acc[nt] = __builtin_amdgcn_mfma_f32_16x16x32_bf16(a, b, acc[nt], 0, 0, 0);
            }
        }
    }

#pragma unroll
    for (int nt = 0; nt < 4; ++nt) {
        const int col = n0 + 16 * nt + l15;
        const float bcol = bias[col];
#pragma unroll
        for (int r = 0; r < 4; ++r) {
            const int row = m0 + 16 * wave + 4 * lq + r;
            Out[(size_t)row * 1024 + col] = acc[nt][r] + bcol;
        }
    }
}

// ---------------------------------------------------------------------------
// Kernel A: inline gate scan (redundant prefix up to chunk j) + dS0 chunk
// outer product. grid (8 chunks, 32 bh), 256 threads (4 waves).
// dS0[bh][j][d][e] = sum_{tau in chunk j} (a*K)[tau][d] * x[tau][e]
// Also writes gc[], ab[] for chunk j.
// ---------------------------------------------------------------------------
__global__ __launch_bounds__(256) void scan_ds0(const float* __restrict__ x,
                                                const float* __restrict__ Kb,
                                                const float* __restrict__ gw_w,
                                                const float* __restrict__ gw_b,
                                                const float* __restrict__ sw_w,
                                                const float* __restrict__ sw_b,
                                                float* __restrict__ gc_out,
                                                float* __restrict__ ab_out,
                                                float* __restrict__ dS0) {
    const int j = blockIdx.x, bh = blockIdx.y;
    const int b = bh >> 4, h = bh & 15;
    const int tid = threadIdx.x;
    const int w = tid >> 6, lane = tid & 63;
    const int l15 = lane & 15, lq = lane >> 4;

    __shared__ float gwl[64], swl[64];
    __shared__ float ctot[8];
    __shared__ float abl[64];
    __shared__ ushort_t KT[64][72];   // [d][tau]
    __shared__ ushort_t VT[64][72];   // [e][tau], V' = a*x

    const size_t base = (size_t)(b * 512) * 1024 + h * 64;

    if (tid < 64) gwl[tid] = gw_w[tid];
    else if (tid < 128) swl[tid - 64] = sw_w[tid - 64];
    __syncthreads();
    const float gwb = gw_b[0], swb = sw_b[0];

    // gate scan over chunks 0..j (wave (i,w) covers chunk cseg = i*4+w)
    const int T = (j + 1) * 64;
    float ps_own = 0.f, dk_own = 0.f;
    for (int i = 0; i * 256 < T; ++i) {
        const int t = i * 256 + tid;
        const int cseg = i * 4 + w;
        if (cseg <= j) {
            const float* xr = x + base + (size_t)t * 1024;
            float dg = 0.f;
#pragma unroll
            for (int d = 0; d < 64; d += 4) {
                float4 xv = *reinterpret_cast<const float4*>(xr + d);
                dg += xv.x * gwl[d] + xv.y * gwl[d + 1] + xv.z * gwl[d + 2] + xv.w * gwl[d + 3];
            }
            float dk = 0.f;
            if (cseg == j) {
                const float* kr = Kb + base + (size_t)t * 1024;
#pragma unroll
                for (int d = 0; d < 64; d += 4) {
                    float4 kv = *reinterpret_cast<const float4*>(kr + d);
                    dk += kv.x * swl[d] + kv.y * swl[d + 1] + kv.z * swl[d + 2] + kv.w * swl[d + 3];
                }
            }
            const float g = sigmoidf_(dg + gwb);
            float ps = logf(fmaxf(g, 1e-6f));
#pragma unroll
            for (int off = 1; off < 64; off <<= 1) {
                float v = __shfl_up(ps, off, 64);
                if (lane >= off) ps += v;
            }
            if (lane == 63) ctot[cseg] = ps;
            if (cseg == j) { ps_own = ps; dk_own = dk; }
        }
    }
    __syncthreads();
    if (w == (j & 3)) {   // the wave that handled chunk j
        float coff = 0.f;
        for (int cc = 0; cc < j; ++cc) coff += ctot[cc];
        const float lsum = coff + ps_own;
        const float Gc = expf(fminf(fmaxf(lsum, -30.f), 30.f)) + 1e-6f;
        const float z = dk_own + swb;
        const float a = z * sigmoidf_(z) / Gc;
        abl[lane] = a;
        gc_out[bh * 512 + j * 64 + lane] = Gc;
        ab_out[bh * 512 + j * 64 + lane] = a;
    }
    __syncthreads();

    // stage K^T and (a*V)^T for this chunk
#pragma unroll
    for (int it = 0; it < 4; ++it) {
        const int idx = tid + it * 256;
        const int rr = idx >> 4;
        const int c4 = (idx & 15) << 2;
        const int tau = j * 64 + rr;
        float4 kv = *reinterpret_cast<const float4*>(Kb + base + (size_t)tau * 1024 + c4);
        float4 xv = *reinterpret_cast<const float4*>(x + base + (size_t)tau * 1024 + c4);
        const float a = abl[rr];
        KT[c4 + 0][rr] = f2bf(kv.x); KT[c4 + 1][rr] = f2bf(kv.y);
        KT[c4 + 2][rr] = f2bf(kv.z); KT[c4 + 3][rr] = f2bf(kv.w);
        VT[c4 + 0][rr] = f2bf(a * xv.x); VT[c4 + 1][rr] = f2bf(a * xv.y);
        VT[c4 + 2][rr] = f2bf(a * xv.z); VT[c4 + 3][rr] = f2bf(a * xv.w);
    }
    __syncthreads();

    f32x4 st[4];
#pragma unroll
    for (int n = 0; n < 4; ++n) st[n] = (f32x4){0.f, 0.f, 0.f, 0.f};
#pragma unroll
    for (int kk = 0; kk < 64; kk += 32) {
        bf16x8 ak = *reinterpret_cast<const bf16x8*>(&KT[16 * w + l15][kk + 8 * lq]);
#pragma unroll
        for (int n = 0; n < 4; ++n) {
            bf16x8 vb = *reinterpret_cast<const bf16x8*>(&VT[16 * n + l15][kk + 8 * lq]);
            st[n] = __builtin_amdgcn_mfma_f32_16x16x32_bf16(ak, vb, st[n], 0, 0, 0);
        }
    }
    float* o = dS0 + (size_t)(bh * 8 + j) * 4096;
#pragma unroll
    for (int n = 0; n < 4; ++n)
#pragma unroll
        for (int r = 0; r < 4; ++r)
            o[(16 * w + 4 * lq + r) * 64 + 16 * n + l15] = st[n][r];
}

// ---------------------------------------------------------------------------
// Kernel B: out0 (GLA output chunk, with inline dS0-prefix) + dS1 emission.
// grid (8 rt, 32 bh), 256 threads.
// ---------------------------------------------------------------------------
__global__ __launch_bounds__(256) void out0_ds1(const float* __restrict__ x,
                                                const float* __restrict__ Qb,
                                                const float* __restrict__ Kb,
                                                const float* __restrict__ C2,
                                                const float* __restrict__ gc,
                                                const float* __restrict__ ab,
                                                const float* __restrict__ dS0,
                                                float* __restrict__ O1out,
                                                float* __restrict__ dS1) {
    const int rt = blockIdx.x, bh = blockIdx.y;
    const int b = bh >> 4, h = bh & 15;
    const int c0 = rt * 64;
    const int tid = threadIdx.x;
    const int w = tid >> 6, lane = tid & 63;
    const int l15 = lane & 15, lq = lane >> 4;

    __shared__ ushort_t Qs[64][72];    // [t][d]
    __shared__ ushort_t Ks[64][72];    // [c][d]
    __shared__ ushort_t VT[64][72];    // [e][tau]
    __shared__ ushort_t K2T[64][72];   // [d][tau]
    __shared__ ushort_t ET[64][72];    // [e][tau]
    __shared__ ushort_t Ps[64][72];    // [t][c]
    __shared__ ushort_t SBt[64][72];   // [e][d]
    __shared__ float av[64], gcv[64];

    const size_t base = (size_t)(b * 512) * 1024 + h * 64;

    // stage Q / K / V^T / k2^T
#pragma unroll
    for (int it = 0; it < 4; ++it) {
        const int idx = tid + it * 256;
        const int rr = idx >> 4;
        const int c4 = (idx & 15) << 2;
        const int tau = c0 + rr;
        float4 qv = *reinterpret_cast<const float4*>(Qb + base + (size_t)tau * 1024 + c4);
        float4 kv = *reinterpret_cast<const float4*>(Kb + base + (size_t)tau * 1024 + c4);
        float4 xv = *reinterpret_cast<const float4*>(x + base + (size_t)tau * 1024 + c4);
        float4 cv = *reinterpret_cast<const float4*>(C2 + base + (size_t)tau * 1024 + c4);
        Qs[rr][c4 + 0] = f2bf(qv.x); Qs[rr][c4 + 1] = f2bf(qv.y);
        Qs[rr][c4 + 2] = f2bf(qv.z); Qs[rr][c4 + 3] = f2bf(qv.w);
        Ks[rr][c4 + 0] = f2bf(kv.x); Ks[rr][c4 + 1] = f2bf(kv.y);
        Ks[rr][c4 + 2] = f2bf(kv.z); Ks[rr][c4 + 3] = f2bf(kv.w);
        VT[c4 + 0][rr] = f2bf(xv.x); VT[c4 + 1][rr] = f2bf(xv.y);
        VT[c4 + 2][rr] = f2bf(xv.z); VT[c4 + 3][rr] = f2bf(xv.w);
        if (tau <= 510) {
            K2T[c4 + 0][rr] = f2bf(sigmoidf_(cv.x * 6.25e-4f));
            K2T[c4 + 1][rr] = f2bf(sigmoidf_(cv.y * 6.25e-4f));
            K2T[c4 + 2][rr] = f2bf(sigmoidf_(cv.z * 6.25e-4f));
            K2T[c4 + 3][rr] = f2bf(sigmoidf_(cv.w * 6.25e-4f));
        } else {
            K2T[c4 + 0][rr] = 0; K2T[c4 + 1][rr] = 0;
            K2T[c4 + 2][rr] = 0; K2T[c4 + 3][rr] = 0;
        }
    }
    if (tid < 64) av[tid] = ab[bh * 512 + c0 + tid];
    else if (tid < 128) gcv[tid - 64] = gc[bh * 512 + c0 + tid - 64];

    // inline prefix of dS0 chunks < rt  ->  SBt (bf16, [e][d])
#pragma unroll
    for (int ii = 0; ii < 4; ++ii) {
        const int flat = tid * 16 + ii * 4;
        float4 s = {0.f, 0.f, 0.f, 0.f};
        for (int jj = 0; jj < rt; ++jj) {
            float4 v = *reinterpret_cast<const float4*>(dS0 + (size_t)(bh * 8 + jj) * 4096 + flat);
            s.x += v.x; s.y += v.y; s.z += v.z; s.w += v.w;
        }
        const int d = flat >> 6, e = flat & 63;
        SBt[e + 0][d] = f2bf(s.x); SBt[e + 1][d] = f2bf(s.y);
        SBt[e + 2][d] = f2bf(s.z); SBt[e + 3][d] = f2bf(s.w);
    }
    __syncthreads();

    // scores
    f32x4 sc[4];
#pragma unroll
    for (int n = 0; n < 4; ++n) sc[n] = (f32x4){0.f, 0.f, 0.f, 0.f};
#pragma unroll
    for (int kk = 0; kk < 64; kk += 32) {
        bf16x8 aq = *reinterpret_cast<const bf16x8*>(&Qs[16 * w + l15][kk + 8 * lq]);
#pragma unroll
        for (int n = 0; n < 4; ++n) {
            bf16x8 bb = *reinterpret_cast<const bf16x8*>(&Ks[16 * n + l15][kk + 8 * lq]);
            sc[n] = __builtin_amdgcn_mfma_f32_16x16x32_bf16(aq, bb, sc[n], 0, 0, 0);
        }
    }
#pragma unroll
    for (int n = 0; n < 4; ++n) {
        const int cl = 16 * n + l15;
#pragma unroll
        for (int r = 0; r < 4; ++r) {
            const int tl = 16 * w + 4 * lq + r;
            Ps[tl][cl] = f2bf(cl <= tl ? sc[n][r] * av[cl] : 0.f);
        }
    }
    __syncthreads();

    // out: oc = Q @ S + P @ V
    f32x4 oc[4];
#pragma unroll
    for (int n = 0; n < 4; ++n) oc[n] = (f32x4){0.f, 0.f, 0.f, 0.f};
#pragma unroll
    for (int kk = 0; kk < 64; kk += 32) {
        bf16x8 aq = *reinterpret_cast<const bf16x8*>(&Qs[16 * w + l15][kk + 8 * lq]);
        bf16x8 ap = *reinterpret_cast<const bf16x8*>(&Ps[16 * w + l15][kk + 8 * lq]);
#pragma unroll
        for (int n = 0; n < 4; ++n) {
            bf16x8 sb = *reinterpret_cast<const bf16x8*>(&SBt[16 * n + l15][kk + 8 * lq]);
            oc[n] = __builtin_amdgcn_mfma_f32_16x16x32_bf16(aq, sb, oc[n], 0, 0, 0);
            bf16x8 vb = *reinterpret_cast<const bf16x8*>(&VT[16 * n + l15][kk + 8 * lq]);
            oc[n] = __builtin_amdgcn_mfma_f32_16x16x32_bf16(ap, vb, oc[n], 0, 0, 0);
        }
    }

    // write O1 chunk; build E^T = (x[tau+1] - O1[tau])^T in LDS
#pragma unroll
    for (int n = 0; n < 4; ++n) {
        const int e = 16 * n + l15;
#pragma unroll
        for (int r = 0; r < 4; ++r) {
            const int tl = 16 * w + 4 * lq + r;
            const int tau = c0 + tl;
            const float val = gcv[tl] * oc[n][r];
            O1out[base + (size_t)tau * 1024 + e] = val;
            float ev = 0.f;
            if (tau <= 510) ev = x[base + (size_t)(tau + 1) * 1024 + e] - val;
            ET[e][tl] = f2bf(ev);
        }
    }
    __syncthreads();

    // dS1 = k2^T @ E
    f32x4 st[4];
#pragma unroll
    for (int n = 0; n < 4; ++n) st[n] = (f32x4){0.f, 0.f, 0.f, 0.f};
#pragma unroll
    for (int kk = 0; kk < 64; kk += 32) {
        bf16x8 ak = *reinterpret_cast<const bf16x8*>(&K2T[16 * w + l15][kk + 8 * lq]);
#pragma unroll
        for (int n = 0; n < 4; ++n) {
            bf16x8 eb = *reinterpret_cast<const bf16x8*>(&ET[16 * n + l15][kk + 8 * lq]);
            st[n] = __builtin_amdgcn_mfma_f32_16x16x32_bf16(ak, eb, st[n], 0, 0, 0);
        }
    }
    float* o = dS1 + (size_t)(bh * 8 + rt) * 4096;
#pragma unroll
    for (int n = 0; n < 4; ++n)
#pragma unroll
        for (int r = 0; r < 4; ++r)
            o[(16 * w + 4 * lq + r) * 64 + 16 * n + l15] = st[n][r];
}

// ---------------------------------------------------------------------------
// Kernel C: MA-branch output (inline dS1-prefix) + final y in bf16.
// grid (8 rt, 32 bh), 256 threads.
// ---------------------------------------------------------------------------
__global__ __launch_bounds__(256) void out1_k(const float* __restrict__ x,
                                              const float* __restrict__ Qb,
                                              const float* __restrict__ C2,
                                              const float* __restrict__ O1,
                                              const float* __restrict__ dS1,
                                              ushort_t* __restrict__ yout) {
    const int rt = blockIdx.x, bh = blockIdx.y;
    const int b = bh >> 4, h = bh & 15;
    const int c0 = rt * 64;
    const int tid = threadIdx.x;
    const int w = tid >> 6, lane = tid & 63;
    const int l15 = lane & 15, lq = lane >> 4;

    __shared__ ushort_t Q2s[64][72];   // [t][d]  (transformed)
    __shared__ ushort_t K2s[64][72];   // [c][d]
    __shared__ ushort_t ET[64][72];    // [e][tau]
    __shared__ ushort_t Ps[64][72];    // [t][c]
    __shared__ ushort_t SBt[64][72];   // [e][d]

    const size_t base = (size_t)(b * 512) * 1024 + h * 64;

#pragma unroll
    for (int it = 0; it < 4; ++it) {
        const int idx = tid + it * 256;
        const int rr = idx >> 4;
        const int c4 = (idx & 15) << 2;
        const int tau = c0 + rr;
        float4 qv = *reinterpret_cast<const float4*>(Qb + base + (size_t)tau * 1024 + c4);
        qv.x = (qv.x < 0.f ? qv.x : 0.02f * qv.x) * 0.125f;
        qv.y = (qv.y < 0.f ? qv.y : 0.02f * qv.y) * 0.125f;
        qv.z = (qv.z < 0.f ? qv.z : 0.02f * qv.z) * 0.125f;
        qv.w = (qv.w < 0.f ? qv.w : 0.02f * qv.w) * 0.125f;
        Q2s[rr][c4 + 0] = f2bf(qv.x); Q2s[rr][c4 + 1] = f2bf(qv.y);
        Q2s[rr][c4 + 2] = f2bf(qv.z); Q2s[rr][c4 + 3] = f2bf(qv.w);
        if (tau <= 510) {
            float4 cv = *reinterpret_cast<const float4*>(C2 + base + (size_t)tau * 1024 + c4);
            K2s[rr][c4 + 0] = f2bf(sigmoidf_(cv.x * 6.25e-4f));
            K2s[rr][c4 + 1] = f2bf(sigmoidf_(cv.y * 6.25e-4f));
            K2s[rr][c4 + 2] = f2bf(sigmoidf_(cv.z * 6.25e-4f));
            K2s[rr][c4 + 3] = f2bf(sigmoidf_(cv.w * 6.25e-4f));
            float4 xv = *reinterpret_cast<const float4*>(x + base + (size_t)(tau + 1) * 1024 + c4);
            float4 ov = *reinterpret_cast<const float4*>(O1 + base + (size_t)tau * 1024 + c4);
            ET[c4 + 0][rr] = f2bf(xv.x - ov.x); ET[c4 + 1][rr] = f2bf(xv.y - ov.y);
            ET[c4 + 2][rr] = f2bf(xv.z - ov.z); ET[c4 + 3][rr] = f2bf(xv.w - ov.w);
        } else {
            K2s[rr][c4 + 0] = 0; K2s[rr][c4 + 1] = 0; K2s[rr][c4 + 2] = 0; K2s[rr][c4 + 3] = 0;
            ET[c4 + 0][rr] = 0; ET[c4 + 1][rr] = 0; ET[c4 + 2][rr] = 0; ET[c4 + 3][rr] = 0;
        }
    }
#pragma unroll
    for (int ii = 0; ii < 4; ++ii) {
        const int flat = tid * 16 + ii * 4;
        float4 s = {0.f, 0.f, 0.f, 0.f};
        for (int jj = 0; jj < rt; ++jj) {
            float4 v = *reinterpret_cast<const float4*>(dS1 + (size_t)(bh * 8 + jj) * 4096 + flat);
            s.x += v.x; s.y += v.y; s.z += v.z; s.w += v.w;
        }
        const int d = flat >> 6, e = flat & 63;
        SBt[e + 0][d] = f2bf(s.x); SBt[e + 1][d] = f2bf(s.y);
        SBt[e + 2][d] = f2bf(s.z); SBt[e + 3][d] = f2bf(s.w);
    }
    __syncthreads();

    f32x4 sc[4];
#pragma unroll
    for (int n = 0; n < 4; ++n) sc[n] = (f32x4){0.f, 0.f, 0.f, 0.f};
#pragma unroll
    for (int kk = 0; kk < 64; kk += 32) {
        bf16x8 aq = *reinterpret_cast<const bf16x8*>(&Q2s[16 * w + l15][kk + 8 * lq]);
#pragma unroll
        for (int n = 0; n < 4; ++n) {
            bf16x8 bb = *reinterpret_cast<const bf16x8*>(&K2s[16 * n + l15][kk + 8 * lq]);
            sc[n] = __builtin_amdgcn_mfma_f32_16x16x32_bf16(aq, bb, sc[n], 0, 0, 0);
        }
    }
#pragma unroll
    for (int n = 0; n < 4; ++n) {
        const int cl = 16 * n + l15;
#pragma unroll
        for (int r = 0; r < 4; ++r) {
            const int tl = 16 * w + 4 * lq + r;
            Ps[tl][cl] = f2bf(cl <= tl ? sc[n][r] : 0.f);
        }
    }
    __syncthreads();

    f32x4 oc[4];
#pragma unroll
    for (int n = 0; n < 4; ++n) oc[n] = (f32x4){0.f, 0.f, 0.f, 0.f};
#pragma unroll
    for (int kk = 0; kk < 64; kk += 32) {
        bf16x8 aq = *reinterpret_cast<const bf16x8*>(&Q2s[16 * w + l15][kk + 8 * lq]);
        bf16x8 ap = *reinterpret_cast<const bf16x8*>(&Ps[16 * w + l15][kk + 8 * lq]);
#pragma unroll
        for (int n = 0; n < 4; ++n) {
            bf16x8 sb = *reinterpret_cast<const bf16x8*>(&SBt[16 * n + l15][kk + 8 * lq]);
            oc[n] = __builtin_amdgcn_mfma_f32_16x16x32_bf16(aq, sb, oc[n], 0, 0, 0);
            bf16x8 eb = *reinterpret_cast<const bf16x8*>(&ET[16 * n + l15][kk + 8 * lq]);
            oc[n] = __builtin_amdgcn_mfma_f32_16x16x32_bf16(ap, eb, oc[n], 0, 0, 0);
        }
    }

#pragma unroll
    for (int n = 0; n < 4; ++n) {
        const int e = 16 * n + l15;
#pragma unroll
        for (int r = 0; r < 4; ++r) {
            const int tp = c0 + 16 * w + 4 * lq + r;
            if (tp <= 510) {
                yout[(size_t)(b * 512 + tp + 1) * 1024 + h * 64 + e] =
                    f2bf(O1[base + (size_t)(tp + 1) * 1024 + e] + oc[n][r]);
            }
        }
    }
    if (rt == 0 && tid < 64)
        yout[(size_t)(b * 512) * 1024 + h * 64 + tid] = f2bf(O1[base + tid]);
}

// ---------------------------------------------------------------------------
extern "C" void kernel_launch(void* const* d_in, const int* in_sizes, int n_in,
                              void* d_out, int out_size, void* d_ws, size_t ws_size,
                              hipStream_t stream) {
    const float* x   = (const float*)d_in[0];
    const float* q1w = (const float*)d_in[1];
    const float* q1b = (const float*)d_in[2];
    const float* k1w = (const float*)d_in[3];
    const float* k1b = (const float*)d_in[4];
    const float* k2w = (const float*)d_in[5];
    const float* k2b = (const float*)d_in[6];
    const float* gww = (const float*)d_in[7];
    const float* gwb = (const float*)d_in[8];
    const float* sww = (const float*)d_in[9];
    const float* swb = (const float*)d_in[10];
    const float* cpw = (const float*)d_in[11];
    const float* cpb = (const float*)d_in[12];
    float* out = (float*)d_out;

    float* ws = (float*)d_ws;
    float* Q    = ws;                       // 1M floats
    float* K    = ws + 1048576;             // 1M
    float* C2   = ws + 2097152;             // 1M
    float* O1   = ws + 3145728;             // 1M
    float* dS0b = ws + 4194304;             // 1M (32*8*4096)
    float* dS1b = ws + 5242880;             // 1M
    float* gcb  = ws + 6291456;             // 16K
    float* abb  = ws + 6307840;             // 16K
    ushort_t* xb  = (ushort_t*)(ws + 6324224);   // 1M ushorts each
    ushort_t* wqb = (ushort_t*)(ws + 6848512);
    ushort_t* wkb = (ushort_t*)(ws + 7372800);
    ushort_t* wcb = (ushort_t*)(ws + 7897088);
    ushort_t* wpb = (ushort_t*)(ws + 8421376);
    ushort_t* ytb = (ushort_t*)(ws + 8945664);
    // end: 9,469,952 floats = 37.9 MB

    cvt5<<<2560, 256, 0, stream>>>(x, q1w, k1w, k2w, cpw, xb, wqb, wkb, wcb, wpb);
    gemm_mfma<<<dim3(16, 16, 3), 256, 0, stream>>>(xb, wqb, wkb, wcb, q1b, k1b, k2b, Q, K, C2);
    scan_ds0<<<dim3(8, 32), 256, 0, stream>>>(x, K, gww, gwb, sww, swb, gcb, abb, dS0b);
    out0_ds1<<<dim3(8, 32), 256, 0, stream>>>(x, Q, K, C2, gcb, abb, dS0b, O1, dS1b);
    out1_k<<<dim3(8, 32), 256, 0, stream>>>(x, Q, C2, O1, dS1b, ytb);
    gemm_mfma<<<dim3(16, 16, 1), 256, 0, stream>>>(ytb, wpb, wpb, wpb, cpb, cpb, cpb, out, out, out);
}

// Round 6
// 80.502 us; speedup vs baseline: 1.4153x; 1.2013x over previous
//
#include <hip/hip_runtime.h>
#include <hip/hip_bf16.h>
#include <math.h>

// Problem constants: B=2, L=512, D=1024, H=16, DH=64. N = B*L = 1024.

typedef unsigned short ushort_t;
typedef __attribute__((ext_vector_type(8))) short bf16x8;
typedef __attribute__((ext_vector_type(4))) float f32x4;

__device__ __forceinline__ float sigmoidf_(float z) { return 1.f / (1.f + expf(-z)); }

__device__ __forceinline__ ushort_t f2bf(float f) {
    __hip_bfloat16 h = __float2bfloat16(f);
    return *reinterpret_cast<ushort_t*>(&h);
}

__device__ __forceinline__ float bf2f(ushort_t u) {
    union { unsigned int i; float f; } v;
    v.i = ((unsigned int)u) << 16;
    return v.f;
}

// global -> LDS async copy, 16 B per lane. LDS dest must be wave-uniform base
// (HW adds lane*16); global src is per-lane.
__device__ __forceinline__ void gl16(const void* g, void* l) {
    __builtin_amdgcn_global_load_lds(
        (const __attribute__((address_space(1))) unsigned int*)g,
        (__attribute__((address_space(3))) unsigned int*)l, 16, 0, 0);
}

// ---------------------------------------------------------------------------
// cvtT: blocks 0..1023: transpose-convert 4 weights fp32[K][N] -> bf16[N][K].
//       blocks 1024..1535: convert x fp32 -> bf16.
// ---------------------------------------------------------------------------
__global__ __launch_bounds__(256) void cvtT(const float* __restrict__ xs,
                                            const float* __restrict__ w0, const float* __restrict__ w1,
                                            const float* __restrict__ w2, const float* __restrict__ w3,
                                            ushort_t* __restrict__ xd,
                                            ushort_t* __restrict__ t0, ushort_t* __restrict__ t1,
                                            ushort_t* __restrict__ t2, ushort_t* __restrict__ t3) {
    const int blk = blockIdx.x;
    const int tid = threadIdx.x;
    if (blk >= 1024) {
        const int off = ((blk - 1024) * 256 + tid) * 8;
        float4 a = *reinterpret_cast<const float4*>(xs + off);
        float4 b = *reinterpret_cast<const float4*>(xs + off + 4);
        union { uint4 v; ushort_t u[8]; } pk;
        pk.u[0] = f2bf(a.x); pk.u[1] = f2bf(a.y); pk.u[2] = f2bf(a.z); pk.u[3] = f2bf(a.w);
        pk.u[4] = f2bf(b.x); pk.u[5] = f2bf(b.y); pk.u[6] = f2bf(b.z); pk.u[7] = f2bf(b.w);
        *reinterpret_cast<uint4*>(xd + off) = pk.v;
        return;
    }
    const int wi = blk >> 8;
    const float* W = wi == 0 ? w0 : wi == 1 ? w1 : wi == 2 ? w2 : w3;
    ushort_t* WT = wi == 0 ? t0 : wi == 1 ? t1 : wi == 2 ? t2 : t3;
    const int tile = blk & 255;
    const int k0 = (tile >> 4) * 64, n0 = (tile & 15) * 64;
    __shared__ ushort_t T[64][72];
#pragma unroll
    for (int it = 0; it < 4; ++it) {
        const int idx = tid + it * 256;
        const int r = idx >> 4;           // k within tile
        const int c4 = (idx & 15) * 4;    // n within tile
        float4 v = *reinterpret_cast<const float4*>(W + (size_t)(k0 + r) * 1024 + n0 + c4);
        T[r][c4 + 0] = f2bf(v.x); T[r][c4 + 1] = f2bf(v.y);
        T[r][c4 + 2] = f2bf(v.z); T[r][c4 + 3] = f2bf(v.w);
    }
    __syncthreads();
    const int n = tid >> 2;
    const int kq = (tid & 3) * 16;
    union { uint4 v[2]; ushort_t u[16]; } pk;
#pragma unroll
    for (int j = 0; j < 16; ++j) pk.u[j] = T[kq + j][n];
    *reinterpret_cast<uint4*>(WT + (size_t)(n0 + n) * 1024 + k0 + kq) = pk.v[0];
    *reinterpret_cast<uint4*>(WT + (size_t)(n0 + n) * 1024 + k0 + kq + 8) = pk.v[1];
}

// ---------------------------------------------------------------------------
// MFMA GEMM with global_load_lds + XOR-swizzled LDS (64x64 tile, BK=64).
// A bf16 [M][K]; WT bf16 [N][K] (pre-transposed).
// mode 1 (z=3): writes bf16 Q / bf16 K / bf16 sigmoid((acc+b)*6.25e-4).
// mode 0 (z=1): writes fp32 acc + bias.
// ---------------------------------------------------------------------------
__global__ __launch_bounds__(256) void gemm_gl(const ushort_t* __restrict__ Ab,
                                               const ushort_t* __restrict__ W0T,
                                               const ushort_t* __restrict__ W1T,
                                               const ushort_t* __restrict__ W2T,
                                               const float* __restrict__ b0,
                                               const float* __restrict__ b1,
                                               const float* __restrict__ b2,
                                               ushort_t* __restrict__ oB0,
                                               ushort_t* __restrict__ oB1,
                                               ushort_t* __restrict__ oB2,
                                               float* __restrict__ oF,
                                               int mode) {
    const int sel = blockIdx.z;
    const ushort_t* WT = sel == 0 ? W0T : sel == 1 ? W1T : W2T;
    const float* bias = sel == 0 ? b0 : sel == 1 ? b1 : b2;
    const int m0 = blockIdx.y * 64, n0 = blockIdx.x * 64;

    __shared__ ushort_t As[4096];   // 64x64 bf16, XOR-swizzled rows
    __shared__ ushort_t Bs[4096];

    const int tid = threadIdx.x;
    const int wave = tid >> 6, lane = tid & 63;
    const int l15 = lane & 15, lq = lane >> 4;

    f32x4 acc[4];
#pragma unroll
    for (int i = 0; i < 4; ++i) acc[i] = (f32x4){0.f, 0.f, 0.f, 0.f};

    for (int k0 = 0; k0 < 1024; k0 += 64) {
        __syncthreads();   // previous MFMA reads done
#pragma unroll
        for (int is = 0; is < 2; ++is) {
            const int p = tid * 16 + is * 4096;            // byte in 8 KB tile
            const int row = p >> 7;                        // tile row
            const int scb = (p & 127) ^ ((row & 7) << 4);  // pre-swizzled src col
            gl16((const char*)Ab + (((size_t)(m0 + row)) << 11) + (k0 << 1) + scb,
                 (char*)As + is * 4096 + wave * 1024);
            gl16((const char*)WT + (((size_t)(n0 + row)) << 11) + (k0 << 1) + scb,
                 (char*)Bs + is * 4096 + wave * 1024);
        }
        __syncthreads();   // drains vmcnt -> data visible

#pragma unroll
        for (int kk = 0; kk < 64; kk += 32) {
            const int cb = (kk + 8 * lq) * 2;
            const int ra = 16 * wave + l15;
            bf16x8 a = *reinterpret_cast<const bf16x8*>(
                (const char*)As + ra * 128 + (cb ^ ((ra & 7) << 4)));
#pragma unroll
            for (int nt = 0; nt < 4; ++nt) {
                const int rb = 16 * nt + l15;
                bf16x8 b = *reinterpret_cast<const bf16x8*>(
                    (const char*)Bs + rb * 128 + (cb ^ ((rb & 7) << 4)));
                acc[nt] = __builtin_amdgcn_mfma_f32_16x16x32_bf16(a, b, acc[nt], 0, 0, 0);
            }
        }
    }

#pragma unroll
    for (int nt = 0; nt < 4; ++nt) {
        const int col = n0 + 16 * nt + l15;
        const float bcol = bias[col];
#pragma unroll
        for (int r = 0; r < 4; ++r) {
            const int row = m0 + 16 * wave + 4 * lq + r;
            const float v = acc[nt][r] + bcol;
            if (mode == 0) {
                oF[(size_t)row * 1024 + col] = v;
            } else if (sel == 0) {
                oB0[(size_t)row * 1024 + col] = f2bf(v);
            } else if (sel == 1) {
                oB1[(size_t)row * 1024 + col] = f2bf(v);
            } else {
                oB2[(size_t)row * 1024 + col] = f2bf(sigmoidf_(v * 6.25e-4f));
            }
        }
    }
}

// ---------------------------------------------------------------------------
// Kernel A: inline gate scan (redundant prefix up to chunk j) + dS0 chunk
// outer product. grid (8 chunks, 32 bh), 256 threads.
// ---------------------------------------------------------------------------
__global__ __launch_bounds__(256) void scan_ds0(const float* __restrict__ x,
                                                const ushort_t* __restrict__ Kb,
                                                const float* __restrict__ gw_w,
                                                const float* __restrict__ gw_b,
                                                const float* __restrict__ sw_w,
                                                const float* __restrict__ sw_b,
                                                float* __restrict__ gc_out,
                                                float* __restrict__ ab_out,
                                                float* __restrict__ dS0) {
    const int j = blockIdx.x, bh = blockIdx.y;
    const int b = bh >> 4, h = bh & 15;
    const int tid = threadIdx.x;
    const int w = tid >> 6, lane = tid & 63;
    const int l15 = lane & 15, lq = lane >> 4;

    __shared__ float gwl[64], swl[64];
    __shared__ float ctot[8];
    __shared__ float abl[64];
    __shared__ ushort_t KT[64][72];   // [d][tau]
    __shared__ ushort_t VT[64][72];   // [e][tau], V' = a*x

    const size_t base = (size_t)(b * 512) * 1024 + h * 64;

    if (tid < 64) gwl[tid] = gw_w[tid];
    else if (tid < 128) swl[tid - 64] = sw_w[tid - 64];
    __syncthreads();
    const float gwb = gw_b[0], swb = sw_b[0];

    const int T = (j + 1) * 64;
    float ps_own = 0.f, dk_own = 0.f;
    for (int i = 0; i * 256 < T; ++i) {
        const int t = i * 256 + tid;
        const int cseg = i * 4 + w;
        if (cseg <= j) {
            const float* xr = x + base + (size_t)t * 1024;
            float dg = 0.f;
#pragma unroll
            for (int d = 0; d < 64; d += 4) {
                float4 xv = *reinterpret_cast<const float4*>(xr + d);
                dg += xv.x * gwl[d] + xv.y * gwl[d + 1] + xv.z * gwl[d + 2] + xv.w * gwl[d + 3];
            }
            float dk = 0.f;
            if (cseg == j) {
                const ushort_t* kr = Kb + base + (size_t)t * 1024;
#pragma unroll
                for (int d = 0; d < 64; d += 8) {
                    union { uint4 v; ushort_t u[8]; } kv;
                    kv.v = *reinterpret_cast<const uint4*>(kr + d);
#pragma unroll
                    for (int q = 0; q < 8; ++q) dk += bf2f(kv.u[q]) * swl[d + q];
                }
            }
            const float g = sigmoidf_(dg + gwb);
            float ps = logf(fmaxf(g, 1e-6f));
#pragma unroll
            for (int off = 1; off < 64; off <<= 1) {
                float v = __shfl_up(ps, off, 64);
                if (lane >= off) ps += v;
            }
            if (lane == 63) ctot[cseg] = ps;
            if (cseg == j) { ps_own = ps; dk_own = dk; }
        }
    }
    __syncthreads();
    if (w == (j & 3)) {
        float coff = 0.f;
        for (int cc = 0; cc < j; ++cc) coff += ctot[cc];
        const float lsum = coff + ps_own;
        const float Gc = expf(fminf(fmaxf(lsum, -30.f), 30.f)) + 1e-6f;
        const float z = dk_own + swb;
        const float a = z * sigmoidf_(z) / Gc;
        abl[lane] = a;
        gc_out[bh * 512 + j * 64 + lane] = Gc;
        ab_out[bh * 512 + j * 64 + lane] = a;
    }
    __syncthreads();

#pragma unroll
    for (int it = 0; it < 4; ++it) {
        const int idx = tid + it * 256;
        const int rr = idx >> 4;
        const int c4 = (idx & 15) << 2;
        const int tau = j * 64 + rr;
        ushort4 kv = *reinterpret_cast<const ushort4*>(Kb + base + (size_t)tau * 1024 + c4);
        float4 xv = *reinterpret_cast<const float4*>(x + base + (size_t)tau * 1024 + c4);
        const float a = abl[rr];
        KT[c4 + 0][rr] = kv.x; KT[c4 + 1][rr] = kv.y;
        KT[c4 + 2][rr] = kv.z; KT[c4 + 3][rr] = kv.w;
        VT[c4 + 0][rr] = f2bf(a * xv.x); VT[c4 + 1][rr] = f2bf(a * xv.y);
        VT[c4 + 2][rr] = f2bf(a * xv.z); VT[c4 + 3][rr] = f2bf(a * xv.w);
    }
    __syncthreads();

    f32x4 st[4];
#pragma unroll
    for (int n = 0; n < 4; ++n) st[n] = (f32x4){0.f, 0.f, 0.f, 0.f};
#pragma unroll
    for (int kk = 0; kk < 64; kk += 32) {
        bf16x8 ak = *reinterpret_cast<const bf16x8*>(&KT[16 * w + l15][kk + 8 * lq]);
#pragma unroll
        for (int n = 0; n < 4; ++n) {
            bf16x8 vb = *reinterpret_cast<const bf16x8*>(&VT[16 * n + l15][kk + 8 * lq]);
            st[n] = __builtin_amdgcn_mfma_f32_16x16x32_bf16(ak, vb, st[n], 0, 0, 0);
        }
    }
    float* o = dS0 + (size_t)(bh * 8 + j) * 4096;
#pragma unroll
    for (int n = 0; n < 4; ++n)
#pragma unroll
        for (int r = 0; r < 4; ++r)
            o[(16 * w + 4 * lq + r) * 64 + 16 * n + l15] = st[n][r];
}

// ---------------------------------------------------------------------------
// Kernel B: GLA output chunk (inline dS0-prefix) + dS1 emission.
// grid (8 rt, 32 bh), 256 threads. Q/K/K2 are bf16 inputs.
// ---------------------------------------------------------------------------
__global__ __launch_bounds__(256) void out0_ds1(const float* __restrict__ x,
                                                const ushort_t* __restrict__ Qb,
                                                const ushort_t* __restrict__ Kb,
                                                const ushort_t* __restrict__ K2b,
                                                const float* __restrict__ gc,
                                                const float* __restrict__ ab,
                                                const float* __restrict__ dS0,
                                                float* __restrict__ O1out,
                                                float* __restrict__ dS1) {
    const int rt = blockIdx.x, bh = blockIdx.y;
    const int b = bh >> 4, h = bh & 15;
    const int c0 = rt * 64;
    const int tid = threadIdx.x;
    const int w = tid >> 6, lane = tid & 63;
    const int l15 = lane & 15, lq = lane >> 4;

    __shared__ ushort_t Qs[64][72];    // [t][d]
    __shared__ ushort_t Ks[64][72];    // [c][d]
    __shared__ ushort_t VT[64][72];    // [e][tau]
    __shared__ ushort_t K2T[64][72];   // [d][tau]
    __shared__ ushort_t ET[64][72];    // [e][tau]
    __shared__ ushort_t Ps[64][72];    // [t][c]
    __shared__ ushort_t SBt[64][72];   // [e][d]
    __shared__ float av[64], gcv[64];

    const size_t base = (size_t)(b * 512) * 1024 + h * 64;

    // plain bf16 copies: Q, K (8 elems/iter)
#pragma unroll
    for (int it = 0; it < 2; ++it) {
        const int idx = tid + it * 256;
        const int rr = idx >> 3;
        const int c8 = (idx & 7) << 3;
        const int tau = c0 + rr;
        *reinterpret_cast<uint4*>(&Qs[rr][c8]) =
            *reinterpret_cast<const uint4*>(Qb + base + (size_t)tau * 1024 + c8);
        *reinterpret_cast<uint4*>(&Ks[rr][c8]) =
            *reinterpret_cast<const uint4*>(Kb + base + (size_t)tau * 1024 + c8);
    }
    // transposed stages: K2^T, V^T(=x^T)
#pragma unroll
    for (int it = 0; it < 4; ++it) {
        const int idx = tid + it * 256;
        const int rr = idx >> 4;
        const int c4 = (idx & 15) << 2;
        const int tau = c0 + rr;
        float4 xv = *reinterpret_cast<const float4*>(x + base + (size_t)tau * 1024 + c4);
        VT[c4 + 0][rr] = f2bf(xv.x); VT[c4 + 1][rr] = f2bf(xv.y);
        VT[c4 + 2][rr] = f2bf(xv.z); VT[c4 + 3][rr] = f2bf(xv.w);
        if (tau <= 510) {
            ushort4 cv = *reinterpret_cast<const ushort4*>(K2b + base + (size_t)tau * 1024 + c4);
            K2T[c4 + 0][rr] = cv.x; K2T[c4 + 1][rr] = cv.y;
            K2T[c4 + 2][rr] = cv.z; K2T[c4 + 3][rr] = cv.w;
        } else {
            K2T[c4 + 0][rr] = 0; K2T[c4 + 1][rr] = 0;
            K2T[c4 + 2][rr] = 0; K2T[c4 + 3][rr] = 0;
        }
    }
    if (tid < 64) av[tid] = ab[bh * 512 + c0 + tid];
    else if (tid < 128) gcv[tid - 64] = gc[bh * 512 + c0 + tid - 64];

    // inline prefix of dS0 chunks < rt -> SBt
#pragma unroll
    for (int ii = 0; ii < 4; ++ii) {
        const int flat = tid * 16 + ii * 4;
        float4 s = {0.f, 0.f, 0.f, 0.f};
        for (int jj = 0; jj < rt; ++jj) {
            float4 v = *reinterpret_cast<const float4*>(dS0 + (size_t)(bh * 8 + jj) * 4096 + flat);
            s.x += v.x; s.y += v.y; s.z += v.z; s.w += v.w;
        }
        const int d = flat >> 6, e = flat & 63;
        SBt[e + 0][d] = f2bf(s.x); SBt[e + 1][d] = f2bf(s.y);
        SBt[e + 2][d] = f2bf(s.z); SBt[e + 3][d] = f2bf(s.w);
    }
    __syncthreads();

    // scores
    f32x4 sc[4];
#pragma unroll
    for (int n = 0; n < 4; ++n) sc[n] = (f32x4){0.f, 0.f, 0.f, 0.f};
#pragma unroll
    for (int kk = 0; kk < 64; kk += 32) {
        bf16x8 aq = *reinterpret_cast<const bf16x8*>(&Qs[16 * w + l15][kk + 8 * lq]);
#pragma unroll
        for (int n = 0; n < 4; ++n) {
            bf16x8 bb = *reinterpret_cast<const bf16x8*>(&Ks[16 * n + l15][kk + 8 * lq]);
            sc[n] = __builtin_amdgcn_mfma_f32_16x16x32_bf16(aq, bb, sc[n], 0, 0, 0);
        }
    }
#pragma unroll
    for (int n = 0; n < 4; ++n) {
        const int cl = 16 * n + l15;
#pragma unroll
        for (int r = 0; r < 4; ++r) {
            const int tl = 16 * w + 4 * lq + r;
            Ps[tl][cl] = f2bf(cl <= tl ? sc[n][r] * av[cl] : 0.f);
        }
    }
    __syncthreads();

    // out: oc = Q @ S + P @ V
    f32x4 oc[4];
#pragma unroll
    for (int n = 0; n < 4; ++n) oc[n] = (f32x4){0.f, 0.f, 0.f, 0.f};
#pragma unroll
    for (int kk = 0; kk < 64; kk += 32) {
        bf16x8 aq = *reinterpret_cast<const bf16x8*>(&Qs[16 * w + l15][kk + 8 * lq]);
        bf16x8 ap = *reinterpret_cast<const bf16x8*>(&Ps[16 * w + l15][kk + 8 * lq]);
#pragma unroll
        for (int n = 0; n < 4; ++n) {
            bf16x8 sb = *reinterpret_cast<const bf16x8*>(&SBt[16 * n + l15][kk + 8 * lq]);
            oc[n] = __builtin_amdgcn_mfma_f32_16x16x32_bf16(aq, sb, oc[n], 0, 0, 0);
            bf16x8 vb = *reinterpret_cast<const bf16x8*>(&VT[16 * n + l15][kk + 8 * lq]);
            oc[n] = __builtin_amdgcn_mfma_f32_16x16x32_bf16(ap, vb, oc[n], 0, 0, 0);
        }
    }

    // write O1 chunk; build E^T
#pragma unroll
    for (int n = 0; n < 4; ++n) {
        const int e = 16 * n + l15;
#pragma unroll
        for (int r = 0; r < 4; ++r) {
            const int tl = 16 * w + 4 * lq + r;
            const int tau = c0 + tl;
            const float val = gcv[tl] * oc[n][r];
            O1out[base + (size_t)tau * 1024 + e] = val;
            float ev = 0.f;
            if (tau <= 510) ev = x[base + (size_t)(tau + 1) * 1024 + e] - val;
            ET[e][tl] = f2bf(ev);
        }
    }
    __syncthreads();

    // dS1 = k2^T @ E
    f32x4 st[4];
#pragma unroll
    for (int n = 0; n < 4; ++n) st[n] = (f32x4){0.f, 0.f, 0.f, 0.f};
#pragma unroll
    for (int kk = 0; kk < 64; kk += 32) {
        bf16x8 ak = *reinterpret_cast<const bf16x8*>(&K2T[16 * w + l15][kk + 8 * lq]);
#pragma unroll
        for (int n = 0; n < 4; ++n) {
            bf16x8 eb = *reinterpret_cast<const bf16x8*>(&ET[16 * n + l15][kk + 8 * lq]);
            st[n] = __builtin_amdgcn_mfma_f32_16x16x32_bf16(ak, eb, st[n], 0, 0, 0);
        }
    }
    float* o = dS1 + (size_t)(bh * 8 + rt) * 4096;
#pragma unroll
    for (int n = 0; n < 4; ++n)
#pragma unroll
        for (int r = 0; r < 4; ++r)
            o[(16 * w + 4 * lq + r) * 64 + 16 * n + l15] = st[n][r];
}

// ---------------------------------------------------------------------------
// Kernel C: MA-branch output (inline dS1-prefix) + final y in bf16.
// ---------------------------------------------------------------------------
__global__ __launch_bounds__(256) void out1_k(const float* __restrict__ x,
                                              const ushort_t* __restrict__ Qb,
                                              const ushort_t* __restrict__ K2b,
                                              const float* __restrict__ O1,
                                              const float* __restrict__ dS1,
                                              ushort_t* __restrict__ yout) {
    const int rt = blockIdx.x, bh = blockIdx.y;
    const int b = bh >> 4, h = bh & 15;
    const int c0 = rt * 64;
    const int tid = threadIdx.x;
    const int w = tid >> 6, lane = tid & 63;
    const int l15 = lane & 15, lq = lane >> 4;

    __shared__ ushort_t Q2s[64][72];   // [t][d]  (transformed)
    __shared__ ushort_t K2s[64][72];   // [c][d]
    __shared__ ushort_t ET[64][72];    // [e][tau]
    __shared__ ushort_t Ps[64][72];    // [t][c]
    __shared__ ushort_t SBt[64][72];   // [e][d]

    const size_t base = (size_t)(b * 512) * 1024 + h * 64;

    // Q transform (bf16 in, bf16 out), K2 copy with tail-row zero
#pragma unroll
    for (int it = 0; it < 2; ++it) {
        const int idx = tid + it * 256;
        const int rr = idx >> 3;
        const int c8 = (idx & 7) << 3;
        const int tau = c0 + rr;
        union { uint4 v; ushort_t u[8]; } qv, qo;
        qv.v = *reinterpret_cast<const uint4*>(Qb + base + (size_t)tau * 1024 + c8);
#pragma unroll
        for (int q = 0; q < 8; ++q) {
            const float f = bf2f(qv.u[q]);
            qo.u[q] = f2bf((f < 0.f ? f : 0.02f * f) * 0.125f);
        }
        *reinterpret_cast<uint4*>(&Q2s[rr][c8]) = qo.v;
        if (tau <= 510) {
            *reinterpret_cast<uint4*>(&K2s[rr][c8]) =
                *reinterpret_cast<const uint4*>(K2b + base + (size_t)tau * 1024 + c8);
        } else {
            *reinterpret_cast<uint4*>(&K2s[rr][c8]) = (uint4){0, 0, 0, 0};
        }
    }
    // E^T
#pragma unroll
    for (int it = 0; it < 4; ++it) {
        const int idx = tid + it * 256;
        const int rr = idx >> 4;
        const int c4 = (idx & 15) << 2;
        const int tau = c0 + rr;
        if (tau <= 510) {
            float4 xv = *reinterpret_cast<const float4*>(x + base + (size_t)(tau + 1) * 1024 + c4);
            float4 ov = *reinterpret_cast<const float4*>(O1 + base + (size_t)tau * 1024 + c4);
            ET[c4 + 0][rr] = f2bf(xv.x - ov.x); ET[c4 + 1][rr] = f2bf(xv.y - ov.y);
            ET[c4 + 2][rr] = f2bf(xv.z - ov.z); ET[c4 + 3][rr] = f2bf(xv.w - ov.w);
        } else {
            ET[c4 + 0][rr] = 0; ET[c4 + 1][rr] = 0; ET[c4 + 2][rr] = 0; ET[c4 + 3][rr] = 0;
        }
    }
#pragma unroll
    for (int ii = 0; ii < 4; ++ii) {
        const int flat = tid * 16 + ii * 4;
        float4 s = {0.f, 0.f, 0.f, 0.f};
        for (int jj = 0; jj < rt; ++jj) {
            float4 v = *reinterpret_cast<const float4*>(dS1 + (size_t)(bh * 8 + jj) * 4096 + flat);
            s.x += v.x; s.y += v.y; s.z += v.z; s.w += v.w;
        }
        const int d = flat >> 6, e = flat & 63;
        SBt[e + 0][d] = f2bf(s.x); SBt[e + 1][d] = f2bf(s.y);
        SBt[e + 2][d] = f2bf(s.z); SBt[e + 3][d] = f2bf(s.w);
    }
    __syncthreads();

    f32x4 sc[4];
#pragma unroll
    for (int n = 0; n < 4; ++n) sc[n] = (f32x4){0.f, 0.f, 0.f, 0.f};
#pragma unroll
    for (int kk = 0; kk < 64; kk += 32) {
        bf16x8 aq = *reinterpret_cast<const bf16x8*>(&Q2s[16 * w + l15][kk + 8 * lq]);
#pragma unroll
        for (int n = 0; n < 4; ++n) {
            bf16x8 bb = *reinterpret_cast<const bf16x8*>(&K2s[16 * n + l15][kk + 8 * lq]);
            sc[n] = __builtin_amdgcn_mfma_f32_16x16x32_bf16(aq, bb, sc[n], 0, 0, 0);
        }
    }
#pragma unroll
    for (int n = 0; n < 4; ++n) {
        const int cl = 16 * n + l15;
#pragma unroll
        for (int r = 0; r < 4; ++r) {
            const int tl = 16 * w + 4 * lq + r;
            Ps[tl][cl] = f2bf(cl <= tl ? sc[n][r] : 0.f);
        }
    }
    __syncthreads();

    f32x4 oc[4];
#pragma unroll
    for (int n = 0; n < 4; ++n) oc[n] = (f32x4){0.f, 0.f, 0.f, 0.f};
#pragma unroll
    for (int kk = 0; kk < 64; kk += 32) {
        bf16x8 aq = *reinterpret_cast<const bf16x8*>(&Q2s[16 * w + l15][kk + 8 * lq]);
        bf16x8 ap = *reinterpret_cast<const bf16x8*>(&Ps[16 * w + l15][kk + 8 * lq]);
#pragma unroll
        for (int n = 0; n < 4; ++n) {
            bf16x8 sb = *reinterpret_cast<const bf16x8*>(&SBt[16 * n + l15][kk + 8 * lq]);
            oc[n] = __builtin_amdgcn_mfma_f32_16x16x32_bf16(aq, sb, oc[n], 0, 0, 0);
            bf16x8 eb = *reinterpret_cast<const bf16x8*>(&ET[16 * n + l15][kk + 8 * lq]);
            oc[n] = __builtin_amdgcn_mfma_f32_16x16x32_bf16(ap, eb, oc[n], 0, 0, 0);
        }
    }

#pragma unroll
    for (int n = 0; n < 4; ++n) {
        const int e = 16 * n + l15;
#pragma unroll
        for (int r = 0; r < 4; ++r) {
            const int tp = c0 + 16 * w + 4 * lq + r;
            if (tp <= 510) {
                yout[(size_t)(b * 512 + tp + 1) * 1024 + h * 64 + e] =
                    f2bf(O1[base + (size_t)(tp + 1) * 1024 + e] + oc[n][r]);
            }
        }
    }
    if (rt == 0 && tid < 64)
        yout[(size_t)(b * 512) * 1024 + h * 64 + tid] = f2bf(O1[base + tid]);
}

// ---------------------------------------------------------------------------
extern "C" void kernel_launch(void* const* d_in, const int* in_sizes, int n_in,
                              void* d_out, int out_size, void* d_ws, size_t ws_size,
                              hipStream_t stream) {
    const float* x   = (const float*)d_in[0];
    const float* q1w = (const float*)d_in[1];
    const float* q1b = (const float*)d_in[2];
    const float* k1w = (const float*)d_in[3];
    const float* k1b = (const float*)d_in[4];
    const float* k2w = (const float*)d_in[5];
    const float* k2b = (const float*)d_in[6];
    const float* gww = (const float*)d_in[7];
    const float* gwb = (const float*)d_in[8];
    const float* sww = (const float*)d_in[9];
    const float* swb = (const float*)d_in[10];
    const float* cpw = (const float*)d_in[11];
    const float* cpb = (const float*)d_in[12];
    float* out = (float*)d_out;

    float* ws = (float*)d_ws;
    float* O1   = ws;                       // 1M floats
    float* dS0b = ws + 1048576;             // 1M
    float* dS1b = ws + 2097152;             // 1M
    float* gcb  = ws + 3145728;             // 16K
    float* abb  = ws + 3162112;             // 16K
    ushort_t* ub = (ushort_t*)(ws + 3178496);
    ushort_t* xb  = ub;                     // 1M ushorts each
    ushort_t* qb  = ub + 1048576;
    ushort_t* kb  = ub + 2097152;
    ushort_t* k2b_ = ub + 3145728;
    ushort_t* wqT = ub + 4194304;
    ushort_t* wkT = ub + 5242880;
    ushort_t* wcT = ub + 6291456;
    ushort_t* wpT = ub + 7340032;
    ushort_t* ytb = ub + 8388608;
    // end: ~31.6 MB of d_ws

    cvtT<<<1536, 256, 0, stream>>>(x, q1w, k1w, k2w, cpw, xb, wqT, wkT, wcT, wpT);
    gemm_gl<<<dim3(16, 16, 3), 256, 0, stream>>>(xb, wqT, wkT, wcT, q1b, k1b, k2b,
                                                 qb, kb, k2b_, nullptr, 1);
    scan_ds0<<<dim3(8, 32), 256, 0, stream>>>(x, kb, gww, gwb, sww, swb, gcb, abb, dS0b);
    out0_ds1<<<dim3(8, 32), 256, 0, stream>>>(x, qb, kb, k2b_, gcb, abb, dS0b, O1, dS1b);
    out1_k<<<dim3(8, 32), 256, 0, stream>>>(x, qb, k2b_, O1, dS1b, ytb);
    gemm_gl<<<dim3(16, 16, 1), 256, 0, stream>>>(ytb, wpT, wpT, wpT, cpb, cpb, cpb,
                                                 nullptr, nullptr, nullptr, out, 0);
}